// Round 1
// baseline (1602.750 us; speedup 1.0000x reference)
//
#include <hip/hip_runtime.h>
#include <hip/hip_bf16.h>

// Problem constants
#define BB 64     // batch
#define NT 128    // text tokens
#define NV 256    // visual tokens
#define DD 512    // feature dim
#define BK 32     // K-chunk
#define ROWS 64   // text rows per gemm block
#define EPSF 1e-7f

__device__ __forceinline__ float bfu(unsigned u) {
    return __uint_as_float(u << 16);
}

__device__ __forceinline__ void unpack8(uint4 p, float f[8]) {
    f[0] = bfu(p.x & 0xffffu); f[1] = bfu(p.x >> 16);
    f[2] = bfu(p.y & 0xffffu); f[3] = bfu(p.y >> 16);
    f[4] = bfu(p.z & 0xffffu); f[5] = bfu(p.z >> 16);
    f[6] = bfu(p.w & 0xffffu); f[7] = bfu(p.w >> 16);
}

// ---------------------------------------------------------------------------
// Kernel 1: L2-normalize rows of text (B*NT rows) and visual (B*NV rows),
// write bf16. One block (256 threads) per row of 512 floats (2/thread).
// ---------------------------------------------------------------------------
__global__ __launch_bounds__(256) void k_normalize(
    const float* __restrict__ tf, const float* __restrict__ vf,
    __hip_bfloat16* __restrict__ tn, __hip_bfloat16* __restrict__ vn) {
    int row = blockIdx.x;
    const float* src;
    __hip_bfloat16* dst;
    if (row < BB * NT) {
        src = tf + (size_t)row * DD;
        dst = tn + (size_t)row * DD;
    } else {
        int r = row - BB * NT;
        src = vf + (size_t)r * DD;
        dst = vn + (size_t)r * DD;
    }
    int tid = threadIdx.x;
    float2 x = ((const float2*)src)[tid];
    float ss = x.x * x.x + x.y * x.y;
    #pragma unroll
    for (int off = 32; off; off >>= 1) ss += __shfl_down(ss, off, 64);
    __shared__ float wsum[4];
    int lane = tid & 63, wid = tid >> 6;
    if (lane == 0) wsum[wid] = ss;
    __syncthreads();
    float tot = wsum[0] + wsum[1] + wsum[2] + wsum[3];
    float scale = 1.0f / fmaxf(sqrtf(tot), 1e-12f);
    __hip_bfloat162 o;
    o.x = __float2bfloat16(x.x * scale);
    o.y = __float2bfloat16(x.y * scale);
    ((__hip_bfloat162*)dst)[tid] = o;
}

// ---------------------------------------------------------------------------
// Kernel 2: for each (i,j) batch pair and 64-row text chunk, compute the
// 64x256 sim tile (K=512), then:
//   - row max over all 256 visual tokens -> max_sims[(i*B+j)*NT + t]
//   - reg partial sum of min(s,0)^2 -> atomicAdd
// grid (NT/ROWS, B, B), block 256.  Micro-tile per thread: 8 rows x 8 cols.
// thread tid: cg = tid&31 (cols cg+32*c), rg = tid>>5 (rows rg*8+r).
// ---------------------------------------------------------------------------
__global__ __launch_bounds__(256) void k_gemm(
    const __hip_bfloat16* __restrict__ tn, const __hip_bfloat16* __restrict__ vn,
    float* __restrict__ max_sims, float* __restrict__ reg_sum) {
    __shared__ float sT[ROWS][BK + 1];   // 64 x 33
    __shared__ float sV[NV][BK + 1];     // 256 x 33
    __shared__ float rw[4];

    const int i = blockIdx.y, j = blockIdx.z;
    const int tt0 = blockIdx.x * ROWS;
    const int tid = threadIdx.x;
    const int cg = tid & 31, rg = tid >> 5;

    const ushort* tbase = (const ushort*)tn + ((size_t)(i * NT + tt0)) * DD;
    const ushort* vbase = (const ushort*)vn + ((size_t)(j * NV)) * DD;

    float acc[8][8];
    #pragma unroll
    for (int r = 0; r < 8; ++r)
        #pragma unroll
        for (int c = 0; c < 8; ++c) acc[r][c] = 0.0f;

    for (int kk = 0; kk < DD; kk += BK) {
        // stage sT: 64x32 bf16 -> fp32. 2048 elems / 256 threads = 8 each.
        {
            int r = tid >> 2;
            int col = (tid & 3) * 8;
            uint4 p = *(const uint4*)(tbase + (size_t)r * DD + kk + col);
            float f[8];
            unpack8(p, f);
            #pragma unroll
            for (int e = 0; e < 8; ++e) sT[r][col + e] = f[e];
        }
        // stage sV: 256x32 bf16 -> fp32. 8192 elems / 256 threads = 32 each.
        #pragma unroll
        for (int p4 = 0; p4 < 4; ++p4) {
            int c = tid + 256 * p4;
            int r = c >> 2;
            int col = (c & 3) * 8;
            uint4 p = *(const uint4*)(vbase + (size_t)r * DD + kk + col);
            float f[8];
            unpack8(p, f);
            #pragma unroll
            for (int e = 0; e < 8; ++e) sV[r][col + e] = f[e];
        }
        __syncthreads();

        #pragma unroll 4
        for (int k = 0; k < BK; ++k) {
            float a[8], b[8];
            #pragma unroll
            for (int r = 0; r < 8; ++r) a[r] = sT[rg * 8 + r][k];
            #pragma unroll
            for (int c = 0; c < 8; ++c) b[c] = sV[cg + 32 * c][k];
            #pragma unroll
            for (int r = 0; r < 8; ++r)
                #pragma unroll
                for (int c = 0; c < 8; ++c)
                    acc[r][c] = fmaf(a[r], b[c], acc[r][c]);
        }
        __syncthreads();
    }

    // Epilogue 1: reg partial = sum min(s,0)^2 over this thread's 64 values
    float rp = 0.0f;
    #pragma unroll
    for (int r = 0; r < 8; ++r)
        #pragma unroll
        for (int c = 0; c < 8; ++c) {
            float m = fminf(acc[r][c], 0.0f);
            rp = fmaf(m, m, rp);
        }

    // Epilogue 2: per-row max over this thread's 8 cols, reduce across cg via
    // reused sT LDS.
    #pragma unroll
    for (int r = 0; r < 8; ++r) {
        float m = acc[r][0];
        #pragma unroll
        for (int c = 1; c < 8; ++c) m = fmaxf(m, acc[r][c]);
        sT[rg * 8 + r][cg] = m;
    }
    __syncthreads();
    if (tid < ROWS) {
        float m = sT[tid][0];
        #pragma unroll
        for (int c = 1; c < 32; ++c) m = fmaxf(m, sT[tid][c]);
        max_sims[((size_t)(i * BB + j)) * NT + tt0 + tid] = m;
    }

    // reduce rp over block, single atomic
    #pragma unroll
    for (int off = 32; off; off >>= 1) rp += __shfl_down(rp, off, 64);
    int lane = tid & 63, wid = tid >> 6;
    if (lane == 0) rw[wid] = rp;
    __syncthreads();
    if (tid == 0) atomicAdd(reg_sum, rw[0] + rw[1] + rw[2] + rw[3]);
}

// ---------------------------------------------------------------------------
// Kernel 3: clip_sims[i][j] = sum_t max_sims[i][j][t]*mask[i][t] /
//                             max(sum_t mask[i][t], EPS)
// grid B*B, block NT(=128).
// ---------------------------------------------------------------------------
__global__ __launch_bounds__(NT) void k_clip(
    const float* __restrict__ max_sims, const int* __restrict__ mask,
    float* __restrict__ clip_sims) {
    int bx = blockIdx.x;
    int i = bx / BB;
    int t = threadIdx.x;
    float m = (float)mask[i * NT + t];
    float v = max_sims[(size_t)bx * NT + t] * m;
    #pragma unroll
    for (int off = 32; off; off >>= 1) {
        v += __shfl_down(v, off, 64);
        m += __shfl_down(m, off, 64);
    }
    __shared__ float a0[2], a1[2];
    int wid = t >> 6;
    if ((t & 63) == 0) { a0[wid] = v; a1[wid] = m; }
    __syncthreads();
    if (t == 0)
        clip_sims[bx] = (a0[0] + a0[1]) / fmaxf(a1[0] + a1[1], EPSF);
}

// ---------------------------------------------------------------------------
// Kernel 4: final scalar loss. Single block, 256 threads.
// ---------------------------------------------------------------------------
__global__ __launch_bounds__(256) void k_loss(
    const float* __restrict__ clip_sims, const float* __restrict__ reg_sum,
    float* __restrict__ out) {
    __shared__ float sc[BB][BB + 1];
    __shared__ float lrow[BB], lcol[BB];
    int tid = threadIdx.x;
    for (int idx = tid; idx < BB * BB; idx += 256)
        sc[idx / BB][idx % BB] = clip_sims[idx];
    __syncthreads();
    if (tid < BB) {
        int i = tid;
        float m = sc[i][0];
        #pragma unroll
        for (int j = 1; j < BB; ++j) m = fmaxf(m, sc[i][j]);
        float s = 0.0f;
        #pragma unroll
        for (int j = 0; j < BB; ++j) s += expf(sc[i][j] - m);
        lrow[i] = m + logf(s) - sc[i][i];
    } else if (tid < 2 * BB) {
        int i = tid - BB;
        float m = sc[0][i];
        #pragma unroll
        for (int j = 1; j < BB; ++j) m = fmaxf(m, sc[j][i]);
        float s = 0.0f;
        #pragma unroll
        for (int j = 0; j < BB; ++j) s += expf(sc[j][i] - m);
        lcol[i] = m + logf(s) - sc[i][i];
    }
    __syncthreads();
    if (tid == 0) {
        float tot = 0.0f;
        for (int i = 0; i < BB; ++i) tot += lrow[i] + lcol[i];
        float contrastive = tot / (2.0f * BB);
        double denom = (double)BB * BB * NT * NV;  // 134217728
        float reg = 0.15f * (float)((double)reg_sum[0] / denom);
        out[0] = contrastive + reg;
    }
}

// ---------------------------------------------------------------------------
extern "C" void kernel_launch(void* const* d_in, const int* in_sizes, int n_in,
                              void* d_out, int out_size, void* d_ws, size_t ws_size,
                              hipStream_t stream) {
    const float* tf = (const float*)d_in[0];   // (B, NT, D) fp32
    const float* vf = (const float*)d_in[1];   // (B, NV, D) fp32
    const int* mask = (const int*)d_in[2];     // (B, NT) int32
    float* out = (float*)d_out;                // scalar fp32

    char* ws = (char*)d_ws;
    size_t tn_bytes = (size_t)BB * NT * DD * sizeof(__hip_bfloat16);  // 8 MB
    size_t vn_bytes = (size_t)BB * NV * DD * sizeof(__hip_bfloat16);  // 16 MB
    size_t ms_bytes = (size_t)BB * BB * NT * sizeof(float);           // 2 MB
    size_t cs_bytes = (size_t)BB * BB * sizeof(float);                // 16 KB

    __hip_bfloat16* tn = (__hip_bfloat16*)ws;
    __hip_bfloat16* vn = (__hip_bfloat16*)(ws + tn_bytes);
    float* max_sims = (float*)(ws + tn_bytes + vn_bytes);
    float* clip_sims = (float*)(ws + tn_bytes + vn_bytes + ms_bytes);
    float* reg_sum = (float*)(ws + tn_bytes + vn_bytes + ms_bytes + cs_bytes);

    hipMemsetAsync(reg_sum, 0, sizeof(float), stream);

    k_normalize<<<BB * NT + BB * NV, 256, 0, stream>>>(tf, vf, tn, vn);
    k_gemm<<<dim3(NT / ROWS, BB, BB), 256, 0, stream>>>(tn, vn, max_sims, reg_sum);
    k_clip<<<BB * BB, NT, 0, stream>>>(max_sims, mask, clip_sims);
    k_loss<<<1, 256, 0, stream>>>(clip_sims, reg_sum, out);
}

// Round 2
// 272.946 us; speedup vs baseline: 5.8720x; 5.8720x over previous
//
#include <hip/hip_runtime.h>
#include <hip/hip_bf16.h>

// Problem constants
#define BB 64     // batch
#define NT 128    // text tokens
#define NV 256    // visual tokens
#define DD 512    // feature dim
#define BK 32     // K-chunk (one 16x16x32 k-step)
#define EPSF 1e-7f

typedef __attribute__((ext_vector_type(8))) short bf16x8;
typedef __attribute__((ext_vector_type(4))) float f32x4;

__device__ __forceinline__ void glds16(const ushort* g, ushort* l) {
    __builtin_amdgcn_global_load_lds(
        (const __attribute__((address_space(1))) unsigned int*)g,
        (__attribute__((address_space(3))) unsigned int*)l, 16, 0, 0);
}

// ---------------------------------------------------------------------------
// Kernel 1: L2-normalize rows of text (B*NT rows) and visual (B*NV rows),
// write bf16. One block (256 threads) per row of 512 floats (2/thread).
// ---------------------------------------------------------------------------
__global__ __launch_bounds__(256) void k_normalize(
    const float* __restrict__ tf, const float* __restrict__ vf,
    __hip_bfloat16* __restrict__ tn, __hip_bfloat16* __restrict__ vn) {
    int row = blockIdx.x;
    const float* src;
    __hip_bfloat16* dst;
    if (row < BB * NT) {
        src = tf + (size_t)row * DD;
        dst = tn + (size_t)row * DD;
    } else {
        int r = row - BB * NT;
        src = vf + (size_t)r * DD;
        dst = vn + (size_t)r * DD;
    }
    int tid = threadIdx.x;
    float2 x = ((const float2*)src)[tid];
    float ss = x.x * x.x + x.y * x.y;
    #pragma unroll
    for (int off = 32; off; off >>= 1) ss += __shfl_down(ss, off, 64);
    __shared__ float wsum[4];
    int lane = tid & 63, wid = tid >> 6;
    if (lane == 0) wsum[wid] = ss;
    __syncthreads();
    float tot = wsum[0] + wsum[1] + wsum[2] + wsum[3];
    float scale = 1.0f / fmaxf(sqrtf(tot), 1e-12f);
    __hip_bfloat162 o;
    o.x = __float2bfloat16(x.x * scale);
    o.y = __float2bfloat16(x.y * scale);
    ((__hip_bfloat162*)dst)[tid] = o;
}

// ---------------------------------------------------------------------------
// Kernel 2 (MFMA): one block per (i,j) batch pair. Block = 512 threads =
// 8 waves arranged 2 (row-groups) x 4 (col-groups); wave tile 64x64 via
// 4x4 tiles of mfma_f32_16x16x32_bf16. K=512 in 16 chunks of 32, staged
// into LDS with global_load_lds width-16 (m97 structure).
// Epilogue: per-row max over 256 visual cols -> max_sims; reg partial
// sum of min(s,0)^2 -> one atomicAdd per block.
// ---------------------------------------------------------------------------
__global__ __launch_bounds__(512, 2) void k_gemm(
    const __hip_bfloat16* __restrict__ tn, const __hip_bfloat16* __restrict__ vn,
    float* __restrict__ max_sims, float* __restrict__ reg_sum) {
    __shared__ ushort sT[NT][BK];    // 128 x 32 bf16 = 8 KB
    __shared__ ushort sV[NV][BK];    // 256 x 32 bf16 = 16 KB
    __shared__ float maxbuf[NT][4];  // row-max partials per col-group
    __shared__ float redw[8];

    const int i = blockIdx.x, j = blockIdx.y;
    const int tid = threadIdx.x;
    const int l = tid & 63, w = tid >> 6;
    const int wr = w >> 2, wc = w & 3;      // wave row-group (0..1), col-group (0..3)
    const int m15 = l & 15, q = l >> 4;     // fragment lane decomposition

    const ushort* tbase = (const ushort*)tn + (size_t)i * NT * DD;
    const ushort* vbase = (const ushort*)vn + (size_t)j * NV * DD;

    // staging indices (flat ushort index within the chunk)
    const int tf0 = tid * 8;                 // sT: 4096 elems, 1 issue
    const int tr = tf0 >> 5, tc = tf0 & 31;
    const int vf0a = tid * 8;                // sV: 8192 elems, 2 issues
    const int vra = vf0a >> 5, vca = vf0a & 31;
    const int vf0b = (512 + tid) * 8;
    const int vrb = vf0b >> 5, vcb = vf0b & 31;

    f32x4 acc[4][4];
    #pragma unroll
    for (int rt = 0; rt < 4; ++rt)
        #pragma unroll
        for (int ct = 0; ct < 4; ++ct) acc[rt][ct] = (f32x4){0.f, 0.f, 0.f, 0.f};

    ushort* sTf = &sT[0][0];
    ushort* sVf = &sV[0][0];

    for (int kk = 0; kk < DD; kk += BK) {
        glds16(tbase + (size_t)tr * DD + kk + tc, sTf + tf0);
        glds16(vbase + (size_t)vra * DD + kk + vca, sVf + vf0a);
        glds16(vbase + (size_t)vrb * DD + kk + vcb, sVf + vf0b);
        __syncthreads();

        bf16x8 a[4], b[4];
        #pragma unroll
        for (int rt = 0; rt < 4; ++rt)
            a[rt] = *(const bf16x8*)&sT[wr * 64 + rt * 16 + m15][q * 8];
        #pragma unroll
        for (int ct = 0; ct < 4; ++ct)
            b[ct] = *(const bf16x8*)&sV[wc * 64 + ct * 16 + m15][q * 8];
        #pragma unroll
        for (int rt = 0; rt < 4; ++rt)
            #pragma unroll
            for (int ct = 0; ct < 4; ++ct)
                acc[rt][ct] = __builtin_amdgcn_mfma_f32_16x16x32_bf16(
                    a[rt], b[ct], acc[rt][ct], 0, 0, 0);
        __syncthreads();
    }

    // Epilogue 1: reg partial = sum of min(s,0)^2 over this lane's 64 values
    float rp = 0.0f;
    #pragma unroll
    for (int rt = 0; rt < 4; ++rt)
        #pragma unroll
        for (int ct = 0; ct < 4; ++ct)
            #pragma unroll
            for (int r = 0; r < 4; ++r) {
                float m = fminf(acc[rt][ct][r], 0.0f);
                rp = fmaf(m, m, rp);
            }

    // Epilogue 2: row max. C/D layout: col = lane&15, row = q*4 + reg.
    // Per (rt, reg): max over ct, then reduce across the 16 cols (m15).
    #pragma unroll
    for (int rt = 0; rt < 4; ++rt)
        #pragma unroll
        for (int r = 0; r < 4; ++r) {
            float m = acc[rt][0][r];
            #pragma unroll
            for (int ct = 1; ct < 4; ++ct) m = fmaxf(m, acc[rt][ct][r]);
            #pragma unroll
            for (int msk = 1; msk < 16; msk <<= 1)
                m = fmaxf(m, __shfl_xor(m, msk, 64));
            if (m15 == 0)
                maxbuf[wr * 64 + rt * 16 + q * 4 + r][wc] = m;
        }

    // Block reduce rp -> one atomic
    #pragma unroll
    for (int off = 32; off; off >>= 1) rp += __shfl_down(rp, off, 64);
    if (l == 0) redw[w] = rp;
    __syncthreads();

    if (tid < NT) {
        float m = fmaxf(fmaxf(maxbuf[tid][0], maxbuf[tid][1]),
                        fmaxf(maxbuf[tid][2], maxbuf[tid][3]));
        max_sims[((size_t)(i * BB + j)) * NT + tid] = m;
    }
    if (tid == 0) {
        float s = 0.0f;
        #pragma unroll
        for (int x = 0; x < 8; ++x) s += redw[x];
        atomicAdd(reg_sum, s);
    }
}

// ---------------------------------------------------------------------------
// Kernel 3: clip_sims[i][j] = masked mean over text tokens
// ---------------------------------------------------------------------------
__global__ __launch_bounds__(NT) void k_clip(
    const float* __restrict__ max_sims, const int* __restrict__ mask,
    float* __restrict__ clip_sims) {
    int bx = blockIdx.x;
    int i = bx / BB;
    int t = threadIdx.x;
    float m = (float)mask[i * NT + t];
    float v = max_sims[(size_t)bx * NT + t] * m;
    #pragma unroll
    for (int off = 32; off; off >>= 1) {
        v += __shfl_down(v, off, 64);
        m += __shfl_down(m, off, 64);
    }
    __shared__ float a0[2], a1[2];
    int wid = t >> 6;
    if ((t & 63) == 0) { a0[wid] = v; a1[wid] = m; }
    __syncthreads();
    if (t == 0)
        clip_sims[bx] = (a0[0] + a0[1]) / fmaxf(a1[0] + a1[1], EPSF);
}

// ---------------------------------------------------------------------------
// Kernel 4: final scalar loss. Single block, 256 threads.
// ---------------------------------------------------------------------------
__global__ __launch_bounds__(256) void k_loss(
    const float* __restrict__ clip_sims, const float* __restrict__ reg_sum,
    float* __restrict__ out) {
    __shared__ float sc[BB][BB + 1];
    __shared__ float lrow[BB], lcol[BB];
    int tid = threadIdx.x;
    for (int idx = tid; idx < BB * BB; idx += 256)
        sc[idx / BB][idx % BB] = clip_sims[idx];
    __syncthreads();
    if (tid < BB) {
        int i = tid;
        float m = sc[i][0];
        #pragma unroll
        for (int j = 1; j < BB; ++j) m = fmaxf(m, sc[i][j]);
        float s = 0.0f;
        #pragma unroll
        for (int j = 0; j < BB; ++j) s += expf(sc[i][j] - m);
        lrow[i] = m + logf(s) - sc[i][i];
    } else if (tid < 2 * BB) {
        int i = tid - BB;
        float m = sc[0][i];
        #pragma unroll
        for (int j = 1; j < BB; ++j) m = fmaxf(m, sc[j][i]);
        float s = 0.0f;
        #pragma unroll
        for (int j = 0; j < BB; ++j) s += expf(sc[j][i] - m);
        lcol[i] = m + logf(s) - sc[i][i];
    }
    __syncthreads();
    if (tid == 0) {
        float tot = 0.0f;
        for (int i = 0; i < BB; ++i) tot += lrow[i] + lcol[i];
        float contrastive = tot / (2.0f * BB);
        double denom = (double)BB * BB * NT * NV;  // 134217728
        float reg = 0.15f * (float)((double)reg_sum[0] / denom);
        out[0] = contrastive + reg;
    }
}

// ---------------------------------------------------------------------------
extern "C" void kernel_launch(void* const* d_in, const int* in_sizes, int n_in,
                              void* d_out, int out_size, void* d_ws, size_t ws_size,
                              hipStream_t stream) {
    const float* tf = (const float*)d_in[0];   // (B, NT, D) fp32
    const float* vf = (const float*)d_in[1];   // (B, NV, D) fp32
    const int* mask = (const int*)d_in[2];     // (B, NT) int32
    float* out = (float*)d_out;                // scalar fp32

    char* ws = (char*)d_ws;
    size_t tn_bytes = (size_t)BB * NT * DD * sizeof(__hip_bfloat16);  // 8 MB
    size_t vn_bytes = (size_t)BB * NV * DD * sizeof(__hip_bfloat16);  // 16 MB
    size_t ms_bytes = (size_t)BB * BB * NT * sizeof(float);           // 2 MB
    size_t cs_bytes = (size_t)BB * BB * sizeof(float);                // 16 KB

    __hip_bfloat16* tn = (__hip_bfloat16*)ws;
    __hip_bfloat16* vn = (__hip_bfloat16*)(ws + tn_bytes);
    float* max_sims = (float*)(ws + tn_bytes + vn_bytes);
    float* clip_sims = (float*)(ws + tn_bytes + vn_bytes + ms_bytes);
    float* reg_sum = (float*)(ws + tn_bytes + vn_bytes + ms_bytes + cs_bytes);

    hipMemsetAsync(reg_sum, 0, sizeof(float), stream);

    k_normalize<<<BB * NT + BB * NV, 256, 0, stream>>>(tf, vf, tn, vn);
    k_gemm<<<dim3(BB, BB), 512, 0, stream>>>(tn, vn, max_sims, reg_sum);
    k_clip<<<BB * BB, NT, 0, stream>>>(max_sims, mask, clip_sims);
    k_loss<<<1, 256, 0, stream>>>(clip_sims, reg_sum, out);
}

// Round 3
// 258.491 us; speedup vs baseline: 6.2004x; 1.0559x over previous
//
#include <hip/hip_runtime.h>
#include <hip/hip_bf16.h>

// Problem constants
#define BB 64     // batch
#define NT 128    // text tokens
#define NV 256    // visual tokens
#define DD 512    // feature dim
#define BK 32     // K-chunk (one 16x16x32 k-step)
#define EPSF 1e-7f

typedef __attribute__((ext_vector_type(8))) short bf16x8;
typedef __attribute__((ext_vector_type(4))) float f32x4;

__device__ __forceinline__ void glds16(const ushort* g, ushort* l) {
    __builtin_amdgcn_global_load_lds(
        (const __attribute__((address_space(1))) unsigned int*)g,
        (__attribute__((address_space(3))) unsigned int*)l, 16, 0, 0);
}

// ---------------------------------------------------------------------------
// Kernel 1: L2-normalize rows of text (B*NT rows) and visual (B*NV rows),
// write bf16. One block (256 threads) per row of 512 floats (2/thread).
// Block 0 also zeroes reg_sum (replaces a memset launch).
// ---------------------------------------------------------------------------
__global__ __launch_bounds__(256) void k_normalize(
    const float* __restrict__ tf, const float* __restrict__ vf,
    __hip_bfloat16* __restrict__ tn, __hip_bfloat16* __restrict__ vn,
    float* __restrict__ reg_sum) {
    int row = blockIdx.x;
    if (row == 0 && threadIdx.x == 0) *reg_sum = 0.0f;
    const float* src;
    __hip_bfloat16* dst;
    if (row < BB * NT) {
        src = tf + (size_t)row * DD;
        dst = tn + (size_t)row * DD;
    } else {
        int r = row - BB * NT;
        src = vf + (size_t)r * DD;
        dst = vn + (size_t)r * DD;
    }
    int tid = threadIdx.x;
    float2 x = ((const float2*)src)[tid];
    float ss = x.x * x.x + x.y * x.y;
    #pragma unroll
    for (int off = 32; off; off >>= 1) ss += __shfl_down(ss, off, 64);
    __shared__ float wsum[4];
    int lane = tid & 63, wid = tid >> 6;
    if (lane == 0) wsum[wid] = ss;
    __syncthreads();
    float tot = wsum[0] + wsum[1] + wsum[2] + wsum[3];
    float scale = 1.0f / fmaxf(sqrtf(tot), 1e-12f);
    __hip_bfloat162 o;
    o.x = __float2bfloat16(x.x * scale);
    o.y = __float2bfloat16(x.y * scale);
    ((__hip_bfloat162*)dst)[tid] = o;
}

// ---------------------------------------------------------------------------
// Kernel 2 (MFMA): one block per (i,j) batch pair. Block = 256 threads =
// 4 waves arranged 2x2; wave tile 64x128 via 4x8 tiles of
// mfma_f32_16x16x32_bf16 (128 acc VGPRs). K=512 in 16 chunks of 32.
// LDS staging via global_load_lds width-16 with an XOR swizzle on the
// 16B-granule index (qp = q ^ ((row>>1)&3)) applied on the global-address
// side (DMA dest must stay lane-contiguous) and mirrored on frag reads:
// spreads each 16-lane read phase across all 32 banks -> no conflicts.
// Epilogue (fused k_clip): per-row max over 256 visual cols -> masked mean
// -> clip_sims[i*B+j]; reg partial sum of min(s,0)^2 -> one atomicAdd.
// ---------------------------------------------------------------------------
__global__ __launch_bounds__(256, 2) void k_gemm(
    const __hip_bfloat16* __restrict__ tn, const __hip_bfloat16* __restrict__ vn,
    const int* __restrict__ mask,
    float* __restrict__ clip_sims, float* __restrict__ reg_sum) {
    __shared__ ushort sT[NT][BK];    // 128 x 32 bf16 = 8 KB
    __shared__ ushort sV[NV][BK];    // 256 x 32 bf16 = 16 KB
    __shared__ float maxbuf[NT][2];  // row-max partials per wave col-group
    __shared__ float redw[4];
    __shared__ float c0[2], c1[2];

    const int i = blockIdx.x, j = blockIdx.y;
    const int tid = threadIdx.x;
    const int l = tid & 63, w = tid >> 6;
    const int wr = w >> 1, wc = w & 1;      // wave row-group (0..1), col-group (0..1)
    const int m15 = l & 15, q = l >> 4;     // fragment lane decomposition

    const ushort* tbase = (const ushort*)tn + (size_t)i * NT * DD;
    const ushort* vbase = (const ushort*)vn + (size_t)j * NV * DD;

    ushort* sTf = &sT[0][0];
    ushort* sVf = &sV[0][0];

    // Staging address precompute (swizzled global offsets, 16B units).
    // Unit f: LDS bytes [f*16, f*16+16) = row (f>>2), phys quad (f&3).
    int t_off[2], t_l[2];
    #pragma unroll
    for (int s = 0; s < 2; ++s) {
        int f = s * 256 + tid;
        int r = f >> 2, qp = f & 3;
        int qs = qp ^ ((r >> 1) & 3);
        t_off[s] = r * DD + qs * 8;
        t_l[s] = f * 8;
    }
    int v_off[4], v_l[4];
    #pragma unroll
    for (int s = 0; s < 4; ++s) {
        int f = s * 256 + tid;
        int r = f >> 2, qp = f & 3;
        int qs = qp ^ ((r >> 1) & 3);
        v_off[s] = r * DD + qs * 8;
        v_l[s] = f * 8;
    }

    // Fragment read byte offsets (swizzled), in ushort units.
    int a_idx[4], b_idx[8];
    #pragma unroll
    for (int rt = 0; rt < 4; ++rt) {
        int row = wr * 64 + rt * 16 + m15;
        int qp = q ^ ((row >> 1) & 3);
        a_idx[rt] = row * BK + qp * 8;
    }
    #pragma unroll
    for (int ct = 0; ct < 8; ++ct) {
        int row = wc * 128 + ct * 16 + m15;
        int qp = q ^ ((row >> 1) & 3);
        b_idx[ct] = row * BK + qp * 8;
    }

    f32x4 acc[4][8];
    #pragma unroll
    for (int rt = 0; rt < 4; ++rt)
        #pragma unroll
        for (int ct = 0; ct < 8; ++ct) acc[rt][ct] = (f32x4){0.f, 0.f, 0.f, 0.f};

    for (int kk = 0; kk < DD; kk += BK) {
        #pragma unroll
        for (int s = 0; s < 2; ++s)
            glds16(tbase + t_off[s] + kk, sTf + t_l[s]);
        #pragma unroll
        for (int s = 0; s < 4; ++s)
            glds16(vbase + v_off[s] + kk, sVf + v_l[s]);
        __syncthreads();

        bf16x8 a[4], b[8];
        #pragma unroll
        for (int rt = 0; rt < 4; ++rt) a[rt] = *(const bf16x8*)(sTf + a_idx[rt]);
        #pragma unroll
        for (int ct = 0; ct < 8; ++ct) b[ct] = *(const bf16x8*)(sVf + b_idx[ct]);
        #pragma unroll
        for (int rt = 0; rt < 4; ++rt)
            #pragma unroll
            for (int ct = 0; ct < 8; ++ct)
                acc[rt][ct] = __builtin_amdgcn_mfma_f32_16x16x32_bf16(
                    a[rt], b[ct], acc[rt][ct], 0, 0, 0);
        __syncthreads();
    }

    // Epilogue 1: reg partial = sum of min(s,0)^2 over this lane's 128 values
    float rp = 0.0f;
    #pragma unroll
    for (int rt = 0; rt < 4; ++rt)
        #pragma unroll
        for (int ct = 0; ct < 8; ++ct)
            #pragma unroll
            for (int r = 0; r < 4; ++r) {
                float m = fminf(acc[rt][ct][r], 0.0f);
                rp = fmaf(m, m, rp);
            }

    // Epilogue 2: row max. C/D layout: col = lane&15, row = q*4 + reg.
    #pragma unroll
    for (int rt = 0; rt < 4; ++rt)
        #pragma unroll
        for (int r = 0; r < 4; ++r) {
            float m = acc[rt][0][r];
            #pragma unroll
            for (int ct = 1; ct < 8; ++ct) m = fmaxf(m, acc[rt][ct][r]);
            #pragma unroll
            for (int msk = 1; msk < 16; msk <<= 1)
                m = fmaxf(m, __shfl_xor(m, msk, 64));
            if (m15 == 0)
                maxbuf[wr * 64 + rt * 16 + q * 4 + r][wc] = m;
        }

    // reg reduce within wave
    #pragma unroll
    for (int off = 32; off; off >>= 1) rp += __shfl_down(rp, off, 64);
    if (l == 0) redw[w] = rp;
    __syncthreads();

    // Fused k_clip: masked mean of row maxes over the 128 text tokens.
    if (tid < NT) {
        float rm = fmaxf(maxbuf[tid][0], maxbuf[tid][1]);
        float mf = (float)mask[i * NT + tid];
        float v = rm * mf;
        #pragma unroll
        for (int off = 32; off; off >>= 1) {
            v += __shfl_down(v, off, 64);
            mf += __shfl_down(mf, off, 64);
        }
        if (l == 0) { c0[w] = v; c1[w] = mf; }
    }
    __syncthreads();
    if (tid == 0) {
        clip_sims[i * BB + j] = (c0[0] + c0[1]) / fmaxf(c1[0] + c1[1], EPSF);
        atomicAdd(reg_sum, redw[0] + redw[1] + redw[2] + redw[3]);
    }
}

// ---------------------------------------------------------------------------
// Kernel 3: final scalar loss. Single block, 256 threads.
// ---------------------------------------------------------------------------
__global__ __launch_bounds__(256) void k_loss(
    const float* __restrict__ clip_sims, const float* __restrict__ reg_sum,
    float* __restrict__ out) {
    __shared__ float sc[BB][BB + 1];
    __shared__ float lrow[BB], lcol[BB];
    int tid = threadIdx.x;
    for (int idx = tid; idx < BB * BB; idx += 256)
        sc[idx / BB][idx % BB] = clip_sims[idx];
    __syncthreads();
    if (tid < BB) {
        int i = tid;
        float m = sc[i][0];
        #pragma unroll
        for (int j = 1; j < BB; ++j) m = fmaxf(m, sc[i][j]);
        float s = 0.0f;
        #pragma unroll
        for (int j = 0; j < BB; ++j) s += expf(sc[i][j] - m);
        lrow[i] = m + logf(s) - sc[i][i];
    } else if (tid < 2 * BB) {
        int i = tid - BB;
        float m = sc[0][i];
        #pragma unroll
        for (int j = 1; j < BB; ++j) m = fmaxf(m, sc[j][i]);
        float s = 0.0f;
        #pragma unroll
        for (int j = 0; j < BB; ++j) s += expf(sc[j][i] - m);
        lcol[i] = m + logf(s) - sc[i][i];
    }
    __syncthreads();
    if (tid == 0) {
        float tot = 0.0f;
        for (int i = 0; i < BB; ++i) tot += lrow[i] + lcol[i];
        float contrastive = tot / (2.0f * BB);
        double denom = (double)BB * BB * NT * NV;  // 134217728
        float reg = 0.15f * (float)((double)reg_sum[0] / denom);
        out[0] = contrastive + reg;
    }
}

// ---------------------------------------------------------------------------
extern "C" void kernel_launch(void* const* d_in, const int* in_sizes, int n_in,
                              void* d_out, int out_size, void* d_ws, size_t ws_size,
                              hipStream_t stream) {
    const float* tf = (const float*)d_in[0];   // (B, NT, D) fp32
    const float* vf = (const float*)d_in[1];   // (B, NV, D) fp32
    const int* mask = (const int*)d_in[2];     // (B, NT) int32
    float* out = (float*)d_out;                // scalar fp32

    char* ws = (char*)d_ws;
    size_t tn_bytes = (size_t)BB * NT * DD * sizeof(__hip_bfloat16);  // 8 MB
    size_t vn_bytes = (size_t)BB * NV * DD * sizeof(__hip_bfloat16);  // 16 MB
    size_t cs_bytes = (size_t)BB * BB * sizeof(float);                // 16 KB

    __hip_bfloat16* tn = (__hip_bfloat16*)ws;
    __hip_bfloat16* vn = (__hip_bfloat16*)(ws + tn_bytes);
    float* clip_sims = (float*)(ws + tn_bytes + vn_bytes);
    float* reg_sum = (float*)(ws + tn_bytes + vn_bytes + cs_bytes);

    k_normalize<<<BB * NT + BB * NV, 256, 0, stream>>>(tf, vf, tn, vn, reg_sum);
    k_gemm<<<dim3(BB, BB), 256, 0, stream>>>(tn, vn, mask, clip_sims, reg_sum);
    k_loss<<<1, 256, 0, stream>>>(clip_sims, reg_sum, out);
}